// Round 7
// baseline (66.836 us; speedup 1.0000x reference)
//
#include <hip/hip_runtime.h>
#include <math.h>

#define NN 18
#define T_STEPS 1280
#define T1LEN 1278   // T-2 (after conv1)
#define T2LEN 1276   // T-4 (after conv2)
#define NPOS1 (T1LEN * NN)   // 23004
#define XTOT  (T_STEPS * NN) // 23040
#define PC1 32
#define NCHUNK1 ((NPOS1 + PC1 - 1) / PC1)  // 719
#define PREPBLK 144                         // 36864 / 256
#define TC2 64
#define NCHUNK2 ((T2LEN + TC2 - 1) / TC2)  // 20
#define NBLK (NCHUNK2 * NN)                // 360

typedef __attribute__((ext_vector_type(8))) short short8;
typedef __attribute__((ext_vector_type(4))) float f32x4;

__device__ __forceinline__ unsigned short f2bf(float v) {
    unsigned u = __builtin_bit_cast(unsigned, v);
    u = u + 0x7fff + ((u >> 16) & 1);          // RNE
    return (unsigned short)(u >> 16);
}
__device__ __forceinline__ float bf2f(unsigned short h) {
    unsigned u = ((unsigned)h) << 16;
    return __builtin_bit_cast(float, u);
}

// =========== K1: [b<719] normalize+conv1(GLU)+cheb(MFMA)+relu -> T1 hi/lo
//             [b>=719] conv2 weight hi/lo split + barrier-counter zeroing ===========
__global__ __launch_bounds__(256) void k_fused1x(const float* __restrict__ x,
        const float* __restrict__ w1a, const float* __restrict__ b1a,
        const float* __restrict__ w1b, const float* __restrict__ b1b,
        const float* __restrict__ w1c, const float* __restrict__ b1c,
        const float* __restrict__ cw, const float* __restrict__ cb,
        const float* __restrict__ w2a, const float* __restrict__ w2b,
        const float* __restrict__ w2c,
        unsigned short* __restrict__ T1hi, unsigned short* __restrict__ T1lo,
        unsigned short* __restrict__ WBhi, unsigned short* __restrict__ WBlo,
        int* __restrict__ cnt1, int* __restrict__ cnt2) {
    int b = blockIdx.x;
    int tid = threadIdx.x;
    if (b >= NCHUNK1) {
        int i = (b - NCHUNK1) * 256 + tid;   // < 36864 exactly
        if (i == 0) { *cnt1 = 0; *cnt2 = 0; }
        int klocal = i & 31;
        int col = (i >> 5) % 192;
        int kb = i / (192 * 32);
        int conv = col >> 6, co = col & 63;
        int k = kb >> 1, ci = (kb & 1) * 32 + klocal;
        const float* w = (conv == 0) ? w2a : (conv == 1 ? w2b : w2c);
        float v = w[co * 192 + ci * 3 + k];
        unsigned short hi = f2bf(v);
        WBhi[i] = hi;
        WBlo[i] = f2bf(v - bf2f(hi));
        return;
    }
    __shared__ float xs[72];
    __shared__ uint4 tileH4[256], tileL4[256];   // 32 pos x 64 bf16, XOR-swizzled
    unsigned short* tileH = (unsigned short*)tileH4;
    unsigned short* tileL = (unsigned short*)tileL4;
    int p0 = b * PC1;
    int np = min(PC1, NPOS1 - p0);
    for (int idx = tid; idx < PC1 + 36; idx += 256) {
        int g = p0 + idx;
        float v = (g < XTOT) ? x[g] : 0.f;
        xs[idx] = v / fmaxf(fabsf(v), 1e-12f);
    }
    __syncthreads();
    int l = tid & 63, w = tid >> 6;
    int c = l;
    {
        float wa0 = w1a[c*3], wa1 = w1a[c*3+1], wa2 = w1a[c*3+2];
        float wb0 = w1b[c*3], wb1 = w1b[c*3+1], wb2 = w1b[c*3+2];
        float wc0 = w1c[c*3], wc1 = w1c[c*3+1], wc2 = w1c[c*3+2];
        float ba = b1a[c], bb = b1b[c], bc = b1c[c];
        #pragma unroll
        for (int j = 0; j < 8; ++j) {
            int pl = w * 8 + j;
            float x0 = xs[pl], x1 = xs[pl + 18], x2 = xs[pl + 36];
            float pa = fmaf(wa2, x2, fmaf(wa1, x1, fmaf(wa0, x0, ba)));
            float pb = fmaf(wb2, x2, fmaf(wb1, x1, fmaf(wb0, x0, bb)));
            float pc_ = fmaf(wc2, x2, fmaf(wc1, x1, fmaf(wc0, x0, bc)));
            float q = 1.0f / (1.0f + expf(-pb));
            float v = fmaxf(pa * q + pc_, 0.f);
            unsigned short hi = f2bf(v);
            int sw = pl * 64 + (((c >> 3) ^ (pl & 7)) << 3) + (c & 7);
            tileH[sw] = hi;
            tileL[sw] = f2bf(v - bf2f(hi));
        }
    }
    int d = w * 16 + (l & 15);
    short8 cbh[2], cbl[2];
    #pragma unroll
    for (int kb = 0; kb < 2; ++kb) {
        #pragma unroll
        for (int j = 0; j < 8; ++j) {
            float v = cw[(kb * 32 + (l >> 4) * 8 + j) * 64 + d];
            unsigned short hi = f2bf(v);
            cbh[kb][j] = (short)hi;
            cbl[kb][j] = (short)f2bf(v - bf2f(hi));
        }
    }
    __syncthreads();
    f32x4 acc[2] = {{0.f,0.f,0.f,0.f},{0.f,0.f,0.f,0.f}};
    #pragma unroll
    for (int kb = 0; kb < 2; ++kb) {
        #pragma unroll
        for (int mt = 0; mt < 2; ++mt) {
            int row = mt * 16 + (l & 15);
            int cbi = kb * 4 + (l >> 4);
            int si = row * 8 + (cbi ^ (row & 7));
            short8 ah = __builtin_bit_cast(short8, tileH4[si]);
            short8 al = __builtin_bit_cast(short8, tileL4[si]);
            acc[mt] = __builtin_amdgcn_mfma_f32_16x16x32_bf16(ah, cbh[kb], acc[mt], 0, 0, 0);
            acc[mt] = __builtin_amdgcn_mfma_f32_16x16x32_bf16(al, cbh[kb], acc[mt], 0, 0, 0);
            acc[mt] = __builtin_amdgcn_mfma_f32_16x16x32_bf16(ah, cbl[kb], acc[mt], 0, 0, 0);
        }
    }
    float cbias = cb[d];
    #pragma unroll
    for (int mt = 0; mt < 2; ++mt) {
        #pragma unroll
        for (int r = 0; r < 4; ++r) {
            int p = mt * 16 + (l >> 4) * 4 + r;
            if (p < np) {
                float v = fmaxf(acc[mt][r] + cbias, 0.f);
                unsigned short hi = f2bf(v);
                int idx = (p0 + p) * 64 + d;
                T1hi[idx] = hi;
                T1lo[idx] = f2bf(v - bf2f(hi));
            }
        }
    }
}

// ---- shared device routine: conv2 MFMA -> h[16] (identical to R5, verified) ----
__device__ __forceinline__ void conv2_compute(
        const unsigned short* __restrict__ T1hi, const unsigned short* __restrict__ T1lo,
        const unsigned short* __restrict__ WBhi, const unsigned short* __restrict__ WBlo,
        const float* __restrict__ b2a, const float* __restrict__ b2b,
        const float* __restrict__ b2c,
        uint4* ldsH, uint4* ldsL,
        int node, int t0, int tid, float h[16], float* s_sum, float* s_sq) {
    int rows_valid = min(66, T1LEN - t0);
    const uint4* gh = (const uint4*)T1hi;
    const uint4* gl = (const uint4*)T1lo;
    for (int idx = tid; idx < 528; idx += 256) {
        int row = idx >> 3, cb2 = idx & 7;
        uint4 vh = {0,0,0,0}, vl = {0,0,0,0};
        if (row < rows_valid) {
            int g = ((t0 + row) * NN + node) * 8 + cb2;
            vh = gh[g]; vl = gl[g];
        }
        int s = row * 8 + (cb2 ^ (row & 7));
        ldsH[s] = vh; ldsL[s] = vl;
    }
    int l = tid & 63, w = tid >> 6;
    int co = w * 16 + (l & 15);
    __syncthreads();
    const uint4* wbh = (const uint4*)WBhi;
    const uint4* wbl = (const uint4*)WBlo;
    f32x4 acc[4][3];
    #pragma unroll
    for (int mt = 0; mt < 4; ++mt)
        #pragma unroll
        for (int ct = 0; ct < 3; ++ct)
            acc[mt][ct] = (f32x4){0.f, 0.f, 0.f, 0.f};
    for (int kb = 0; kb < 6; ++kb) {
        short8 bh[3], bl[3];
        #pragma unroll
        for (int ct = 0; ct < 3; ++ct) {
            int col = (w + 4 * ct) * 16 + (l & 15);
            int gi = (kb * 192 + col) * 4 + (l >> 4);
            bh[ct] = __builtin_bit_cast(short8, wbh[gi]);
            bl[ct] = __builtin_bit_cast(short8, wbl[gi]);
        }
        #pragma unroll
        for (int mt = 0; mt < 4; ++mt) {
            int row = mt * 16 + (l & 15) + (kb >> 1);
            int cb2 = (kb & 1) * 4 + (l >> 4);
            int si = row * 8 + (cb2 ^ (row & 7));
            short8 ah = __builtin_bit_cast(short8, ldsH[si]);
            short8 al = __builtin_bit_cast(short8, ldsL[si]);
            acc[mt][0] = __builtin_amdgcn_mfma_f32_16x16x32_bf16(ah, bh[0], acc[mt][0], 0, 0, 0);
            acc[mt][1] = __builtin_amdgcn_mfma_f32_16x16x32_bf16(ah, bh[1], acc[mt][1], 0, 0, 0);
            acc[mt][2] = __builtin_amdgcn_mfma_f32_16x16x32_bf16(ah, bh[2], acc[mt][2], 0, 0, 0);
            acc[mt][0] = __builtin_amdgcn_mfma_f32_16x16x32_bf16(al, bh[0], acc[mt][0], 0, 0, 0);
            acc[mt][1] = __builtin_amdgcn_mfma_f32_16x16x32_bf16(al, bh[1], acc[mt][1], 0, 0, 0);
            acc[mt][2] = __builtin_amdgcn_mfma_f32_16x16x32_bf16(al, bh[2], acc[mt][2], 0, 0, 0);
            acc[mt][0] = __builtin_amdgcn_mfma_f32_16x16x32_bf16(ah, bl[0], acc[mt][0], 0, 0, 0);
            acc[mt][1] = __builtin_amdgcn_mfma_f32_16x16x32_bf16(ah, bl[1], acc[mt][1], 0, 0, 0);
            acc[mt][2] = __builtin_amdgcn_mfma_f32_16x16x32_bf16(ah, bl[2], acc[mt][2], 0, 0, 0);
        }
    }
    float ba = b2a[co], bb = b2b[co], bc = b2c[co];
    float ssum = 0.f, ssq = 0.f;
    #pragma unroll
    for (int mt = 0; mt < 4; ++mt) {
        #pragma unroll
        for (int r = 0; r < 4; ++r) {
            int t = t0 + mt * 16 + (l >> 4) * 4 + r;
            float hv = 0.f;
            if (t < T2LEN) {
                float P = acc[mt][0][r] + ba, Q = acc[mt][1][r] + bb, Cc = acc[mt][2][r] + bc;
                float qs = 1.f / (1.f + expf(-Q));
                hv = fmaxf(fmaf(P, qs, Cc), 0.f);
                ssum += hv;
                ssq = fmaf(hv, hv, ssq);
            }
            h[mt * 4 + r] = hv;
        }
    }
    *s_sum = ssum; *s_sq = ssq;
}

// =========== K2: conv2 + BN partials + global software barrier + BN/dot + last-block final ===========
__global__ __launch_bounds__(256, 2) void k_conv2dot(
        const unsigned short* __restrict__ T1hi, const unsigned short* __restrict__ T1lo,
        const unsigned short* __restrict__ WBhi, const unsigned short* __restrict__ WBlo,
        const float* __restrict__ b2a, const float* __restrict__ b2b,
        const float* __restrict__ b2c,
        const float* __restrict__ gamma, const float* __restrict__ beta,
        const float* __restrict__ fcw, const float* __restrict__ fcb,
        float* parts, float* dpart, int* cnt1, int* cnt2,
        float* __restrict__ out) {
    __shared__ uint4 ldsH[528], ldsL[528];
    __shared__ float red1[256], red2[256];
    __shared__ float pl[2 * NCHUNK2];
    __shared__ int lastFlag;
    int b = blockIdx.x;
    int node = b / NCHUNK2, chunk = b % NCHUNK2;
    int t0 = chunk * TC2;
    int tid = threadIdx.x;
    float h[16], s_sum, s_sq;
    conv2_compute(T1hi, T1lo, WBhi, WBlo, b2a, b2b, b2c, ldsH, ldsL,
                  node, t0, tid, h, &s_sum, &s_sq);
    red1[tid] = s_sum; red2[tid] = s_sq;
    __syncthreads();
    for (int off = 128; off > 0; off >>= 1) {
        if (tid < off) { red1[tid] += red1[tid + off]; red2[tid] += red2[tid + off]; }
        __syncthreads();
    }
    // ---- publish partials + single-stage global barrier (all 360 blocks resident) ----
    if (tid == 0) {
        __hip_atomic_store(&parts[b * 2],     red1[0], __ATOMIC_RELEASE, __HIP_MEMORY_SCOPE_AGENT);
        __hip_atomic_store(&parts[b * 2 + 1], red2[0], __ATOMIC_RELEASE, __HIP_MEMORY_SCOPE_AGENT);
        __threadfence();
        atomicAdd(cnt1, 1);
        while (__hip_atomic_load(cnt1, __ATOMIC_ACQUIRE, __HIP_MEMORY_SCOPE_AGENT) < NBLK)
            __builtin_amdgcn_s_sleep(2);
    }
    __syncthreads();
    if (tid < 2 * NCHUNK2)
        pl[tid] = __hip_atomic_load(&parts[node * 2 * NCHUNK2 + tid],
                                    __ATOMIC_ACQUIRE, __HIP_MEMORY_SCOPE_AGENT);
    __syncthreads();
    // ---- stats finalize (fixed order, deterministic) ----
    float s = 0.f, q = 0.f;
    #pragma unroll
    for (int i = 0; i < NCHUNK2; ++i) { s += pl[2 * i]; q += pl[2 * i + 1]; }
    float cntf = (float)(T2LEN * 64);
    float mean = s / cntf;
    float var = q / cntf - mean * mean;
    float istd = rsqrtf(var + 1e-5f);
    float g = gamma[node], bt = beta[node];
    int l = tid & 63, w = tid >> 6;
    int co = w * 16 + (l & 15);
    float acc = 0.f;
    #pragma unroll
    for (int mt = 0; mt < 4; ++mt) {
        #pragma unroll
        for (int r = 0; r < 4; ++r) {
            int t = t0 + mt * 16 + (l >> 4) * 4 + r;
            if (t < T2LEN) {
                float v = fmaxf((h[mt * 4 + r] - mean) * istd * g + bt, 0.f);
                acc = fmaf(v, fcw[(t * NN + node) * 64 + co], acc);
            }
        }
    }
    red1[tid] = acc;
    __syncthreads();
    for (int off = 128; off > 0; off >>= 1) {
        if (tid < off) red1[tid] += red1[tid + off];
        __syncthreads();
    }
    if (tid == 0) {
        __hip_atomic_store(&dpart[b], red1[0], __ATOMIC_RELEASE, __HIP_MEMORY_SCOPE_AGENT);
        __threadfence();
        int old = atomicAdd(cnt2, 1);
        lastFlag = (old == NBLK - 1);
    }
    __syncthreads();
    // ---- last block reduces (same order as old k_final: strided then tree) ----
    if (lastFlag) {
        float v = 0.f;
        for (int i = tid; i < NBLK; i += 256)
            v += __hip_atomic_load(&dpart[i], __ATOMIC_ACQUIRE, __HIP_MEMORY_SCOPE_AGENT);
        red1[tid] = v;
        __syncthreads();
        for (int off = 128; off > 0; off >>= 1) {
            if (tid < off) red1[tid] += red1[tid + off];
            __syncthreads();
        }
        if (tid == 0) out[0] = red1[0] + fcb[0];
    }
}

extern "C" void kernel_launch(void* const* d_in, const int* in_sizes, int n_in,
                              void* d_out, int out_size, void* d_ws, size_t ws_size,
                              hipStream_t stream) {
    const float* x     = (const float*)d_in[0];
    // d_in[1] edge_index, d_in[2] edge_weight: unused (ChebConv K=1 -> identity only)
    const float* w1a   = (const float*)d_in[3];
    const float* b1a   = (const float*)d_in[4];
    const float* w1b   = (const float*)d_in[5];
    const float* b1b   = (const float*)d_in[6];
    const float* w1c   = (const float*)d_in[7];
    const float* b1c   = (const float*)d_in[8];
    const float* chw   = (const float*)d_in[9];
    const float* chb   = (const float*)d_in[10];
    const float* w2a   = (const float*)d_in[11];
    const float* b2a   = (const float*)d_in[12];
    const float* w2b   = (const float*)d_in[13];
    const float* b2b   = (const float*)d_in[14];
    const float* w2c   = (const float*)d_in[15];
    const float* b2c   = (const float*)d_in[16];
    const float* gamma = (const float*)d_in[17];
    const float* beta  = (const float*)d_in[18];
    const float* fcw   = (const float*)d_in[19];
    const float* fcb   = (const float*)d_in[20];
    float* out = (float*)d_out;

    char* base = (char*)d_ws;
    unsigned short* T1hi  = (unsigned short*)(base);           // 2944512 B
    unsigned short* T1lo  = (unsigned short*)(base + 2944512); // 2944512 B
    unsigned short* WBhi  = (unsigned short*)(base + 5889024); // 73728 B
    unsigned short* WBlo  = (unsigned short*)(base + 5962752); // 73728 B
    float*          parts = (float*)(base + 6036480);          // 720 f
    float*          dpart = (float*)(base + 6039360);          // 360 f
    int*            cnt1  = (int*)(base + 6040800);
    int*            cnt2  = (int*)(base + 6040804);

    k_fused1x<<<NCHUNK1 + PREPBLK, 256, 0, stream>>>(
        x, w1a, b1a, w1b, b1b, w1c, b1c, chw, chb,
        w2a, w2b, w2c, T1hi, T1lo, WBhi, WBlo, cnt1, cnt2);
    k_conv2dot<<<NBLK, 256, 0, stream>>>(
        T1hi, T1lo, WBhi, WBlo, b2a, b2b, b2c,
        gamma, beta, fcw, fcb, parts, dpart, cnt1, cnt2, out);
}

// Round 8
// 47.579 us; speedup vs baseline: 1.4048x; 1.4048x over previous
//
#include <hip/hip_runtime.h>
#include <math.h>

#define NN 18
#define T_STEPS 1280
#define T1LEN 1278   // T-2 (after conv1)
#define T2LEN 1276   // T-4 (after conv2)
#define NPOS1 (T1LEN * NN)   // 23004
#define XTOT  (T_STEPS * NN) // 23040
#define PC1 32
#define NCHUNK1 ((NPOS1 + PC1 - 1) / PC1)  // 719
#define PREPBLK 144                         // 36864 / 256
#define TC2 64
#define NCHUNK2 ((T2LEN + TC2 - 1) / TC2)  // 20
#define NBLK (NCHUNK2 * NN)                // 360
#define NCNTRS 37                           // 18 node-barrier + 18 node-elect + 1 global

typedef __attribute__((ext_vector_type(8))) short short8;
typedef __attribute__((ext_vector_type(4))) float f32x4;

__device__ __forceinline__ unsigned short f2bf(float v) {
    unsigned u = __builtin_bit_cast(unsigned, v);
    u = u + 0x7fff + ((u >> 16) & 1);          // RNE
    return (unsigned short)(u >> 16);
}
__device__ __forceinline__ float bf2f(unsigned short h) {
    unsigned u = ((unsigned)h) << 16;
    return __builtin_bit_cast(float, u);
}

// =========== K1: [b<719] normalize+conv1(GLU)+cheb(MFMA)+relu -> T1 hi/lo
//             [b>=719] conv2 weight hi/lo split + counter zeroing ===========
__global__ __launch_bounds__(256) void k_fused1x(const float* __restrict__ x,
        const float* __restrict__ w1a, const float* __restrict__ b1a,
        const float* __restrict__ w1b, const float* __restrict__ b1b,
        const float* __restrict__ w1c, const float* __restrict__ b1c,
        const float* __restrict__ cw, const float* __restrict__ cb,
        const float* __restrict__ w2a, const float* __restrict__ w2b,
        const float* __restrict__ w2c,
        unsigned short* __restrict__ T1hi, unsigned short* __restrict__ T1lo,
        unsigned short* __restrict__ WBhi, unsigned short* __restrict__ WBlo,
        int* __restrict__ cnts) {
    int b = blockIdx.x;
    int tid = threadIdx.x;
    if (b >= NCHUNK1) {
        int i = (b - NCHUNK1) * 256 + tid;   // < 36864 exactly
        if (b == NCHUNK1 && tid < NCNTRS) cnts[tid * 32] = 0;  // 128B-strided counters
        int klocal = i & 31;
        int col = (i >> 5) % 192;
        int kb = i / (192 * 32);
        int conv = col >> 6, co = col & 63;
        int k = kb >> 1, ci = (kb & 1) * 32 + klocal;
        const float* w = (conv == 0) ? w2a : (conv == 1 ? w2b : w2c);
        float v = w[co * 192 + ci * 3 + k];
        unsigned short hi = f2bf(v);
        WBhi[i] = hi;
        WBlo[i] = f2bf(v - bf2f(hi));
        return;
    }
    __shared__ float xs[72];
    __shared__ uint4 tileH4[256], tileL4[256];   // 32 pos x 64 bf16, XOR-swizzled
    unsigned short* tileH = (unsigned short*)tileH4;
    unsigned short* tileL = (unsigned short*)tileL4;
    int p0 = b * PC1;
    int np = min(PC1, NPOS1 - p0);
    for (int idx = tid; idx < PC1 + 36; idx += 256) {
        int g = p0 + idx;
        float v = (g < XTOT) ? x[g] : 0.f;
        xs[idx] = v / fmaxf(fabsf(v), 1e-12f);
    }
    __syncthreads();
    int l = tid & 63, w = tid >> 6;
    int c = l;
    {
        float wa0 = w1a[c*3], wa1 = w1a[c*3+1], wa2 = w1a[c*3+2];
        float wb0 = w1b[c*3], wb1 = w1b[c*3+1], wb2 = w1b[c*3+2];
        float wc0 = w1c[c*3], wc1 = w1c[c*3+1], wc2 = w1c[c*3+2];
        float ba = b1a[c], bb = b1b[c], bc = b1c[c];
        #pragma unroll
        for (int j = 0; j < 8; ++j) {
            int pl = w * 8 + j;
            float x0 = xs[pl], x1 = xs[pl + 18], x2 = xs[pl + 36];
            float pa = fmaf(wa2, x2, fmaf(wa1, x1, fmaf(wa0, x0, ba)));
            float pb = fmaf(wb2, x2, fmaf(wb1, x1, fmaf(wb0, x0, bb)));
            float pc_ = fmaf(wc2, x2, fmaf(wc1, x1, fmaf(wc0, x0, bc)));
            float q = 1.0f / (1.0f + expf(-pb));
            float v = fmaxf(pa * q + pc_, 0.f);
            unsigned short hi = f2bf(v);
            int sw = pl * 64 + (((c >> 3) ^ (pl & 7)) << 3) + (c & 7);
            tileH[sw] = hi;
            tileL[sw] = f2bf(v - bf2f(hi));
        }
    }
    int d = w * 16 + (l & 15);
    short8 cbh[2], cbl[2];
    #pragma unroll
    for (int kb = 0; kb < 2; ++kb) {
        #pragma unroll
        for (int j = 0; j < 8; ++j) {
            float v = cw[(kb * 32 + (l >> 4) * 8 + j) * 64 + d];
            unsigned short hi = f2bf(v);
            cbh[kb][j] = (short)hi;
            cbl[kb][j] = (short)f2bf(v - bf2f(hi));
        }
    }
    __syncthreads();
    f32x4 acc[2] = {{0.f,0.f,0.f,0.f},{0.f,0.f,0.f,0.f}};
    #pragma unroll
    for (int kb = 0; kb < 2; ++kb) {
        #pragma unroll
        for (int mt = 0; mt < 2; ++mt) {
            int row = mt * 16 + (l & 15);
            int cbi = kb * 4 + (l >> 4);
            int si = row * 8 + (cbi ^ (row & 7));
            short8 ah = __builtin_bit_cast(short8, tileH4[si]);
            short8 al = __builtin_bit_cast(short8, tileL4[si]);
            acc[mt] = __builtin_amdgcn_mfma_f32_16x16x32_bf16(ah, cbh[kb], acc[mt], 0, 0, 0);
            acc[mt] = __builtin_amdgcn_mfma_f32_16x16x32_bf16(al, cbh[kb], acc[mt], 0, 0, 0);
            acc[mt] = __builtin_amdgcn_mfma_f32_16x16x32_bf16(ah, cbl[kb], acc[mt], 0, 0, 0);
        }
    }
    float cbias = cb[d];
    #pragma unroll
    for (int mt = 0; mt < 2; ++mt) {
        #pragma unroll
        for (int r = 0; r < 4; ++r) {
            int p = mt * 16 + (l >> 4) * 4 + r;
            if (p < np) {
                float v = fmaxf(acc[mt][r] + cbias, 0.f);
                unsigned short hi = f2bf(v);
                int idx = (p0 + p) * 64 + d;
                T1hi[idx] = hi;
                T1lo[idx] = f2bf(v - bf2f(hi));
            }
        }
    }
}

// ---- shared device routine: conv2 MFMA -> h[16] (identical to R5, verified) ----
__device__ __forceinline__ void conv2_compute(
        const unsigned short* __restrict__ T1hi, const unsigned short* __restrict__ T1lo,
        const unsigned short* __restrict__ WBhi, const unsigned short* __restrict__ WBlo,
        const float* __restrict__ b2a, const float* __restrict__ b2b,
        const float* __restrict__ b2c,
        uint4* ldsH, uint4* ldsL,
        int node, int t0, int tid, float h[16], float* s_sum, float* s_sq) {
    int rows_valid = min(66, T1LEN - t0);
    const uint4* gh = (const uint4*)T1hi;
    const uint4* gl = (const uint4*)T1lo;
    for (int idx = tid; idx < 528; idx += 256) {
        int row = idx >> 3, cb2 = idx & 7;
        uint4 vh = {0,0,0,0}, vl = {0,0,0,0};
        if (row < rows_valid) {
            int g = ((t0 + row) * NN + node) * 8 + cb2;
            vh = gh[g]; vl = gl[g];
        }
        int s = row * 8 + (cb2 ^ (row & 7));
        ldsH[s] = vh; ldsL[s] = vl;
    }
    int l = tid & 63, w = tid >> 6;
    int co = w * 16 + (l & 15);
    __syncthreads();
    const uint4* wbh = (const uint4*)WBhi;
    const uint4* wbl = (const uint4*)WBlo;
    f32x4 acc[4][3];
    #pragma unroll
    for (int mt = 0; mt < 4; ++mt)
        #pragma unroll
        for (int ct = 0; ct < 3; ++ct)
            acc[mt][ct] = (f32x4){0.f, 0.f, 0.f, 0.f};
    for (int kb = 0; kb < 6; ++kb) {
        short8 bh[3], bl[3];
        #pragma unroll
        for (int ct = 0; ct < 3; ++ct) {
            int col = (w + 4 * ct) * 16 + (l & 15);
            int gi = (kb * 192 + col) * 4 + (l >> 4);
            bh[ct] = __builtin_bit_cast(short8, wbh[gi]);
            bl[ct] = __builtin_bit_cast(short8, wbl[gi]);
        }
        #pragma unroll
        for (int mt = 0; mt < 4; ++mt) {
            int row = mt * 16 + (l & 15) + (kb >> 1);
            int cb2 = (kb & 1) * 4 + (l >> 4);
            int si = row * 8 + (cb2 ^ (row & 7));
            short8 ah = __builtin_bit_cast(short8, ldsH[si]);
            short8 al = __builtin_bit_cast(short8, ldsL[si]);
            acc[mt][0] = __builtin_amdgcn_mfma_f32_16x16x32_bf16(ah, bh[0], acc[mt][0], 0, 0, 0);
            acc[mt][1] = __builtin_amdgcn_mfma_f32_16x16x32_bf16(ah, bh[1], acc[mt][1], 0, 0, 0);
            acc[mt][2] = __builtin_amdgcn_mfma_f32_16x16x32_bf16(ah, bh[2], acc[mt][2], 0, 0, 0);
            acc[mt][0] = __builtin_amdgcn_mfma_f32_16x16x32_bf16(al, bh[0], acc[mt][0], 0, 0, 0);
            acc[mt][1] = __builtin_amdgcn_mfma_f32_16x16x32_bf16(al, bh[1], acc[mt][1], 0, 0, 0);
            acc[mt][2] = __builtin_amdgcn_mfma_f32_16x16x32_bf16(al, bh[2], acc[mt][2], 0, 0, 0);
            acc[mt][0] = __builtin_amdgcn_mfma_f32_16x16x32_bf16(ah, bl[0], acc[mt][0], 0, 0, 0);
            acc[mt][1] = __builtin_amdgcn_mfma_f32_16x16x32_bf16(ah, bl[1], acc[mt][1], 0, 0, 0);
            acc[mt][2] = __builtin_amdgcn_mfma_f32_16x16x32_bf16(ah, bl[2], acc[mt][2], 0, 0, 0);
        }
    }
    float ba = b2a[co], bb = b2b[co], bc = b2c[co];
    float ssum = 0.f, ssq = 0.f;
    #pragma unroll
    for (int mt = 0; mt < 4; ++mt) {
        #pragma unroll
        for (int r = 0; r < 4; ++r) {
            int t = t0 + mt * 16 + (l >> 4) * 4 + r;
            float hv = 0.f;
            if (t < T2LEN) {
                float P = acc[mt][0][r] + ba, Q = acc[mt][1][r] + bb, Cc = acc[mt][2][r] + bc;
                float qs = 1.f / (1.f + expf(-Q));
                hv = fmaxf(fmaf(P, qs, Cc), 0.f);
                ssum += hv;
                ssq = fmaf(hv, hv, ssq);
            }
            h[mt * 4 + r] = hv;
        }
    }
    *s_sum = ssum; *s_sq = ssq;
}

// =========== K2: conv2 + per-node barrier + BN/dot + hierarchical final ===========
__global__ __launch_bounds__(256, 2) void k_conv2dot(
        const unsigned short* __restrict__ T1hi, const unsigned short* __restrict__ T1lo,
        const unsigned short* __restrict__ WBhi, const unsigned short* __restrict__ WBlo,
        const float* __restrict__ b2a, const float* __restrict__ b2b,
        const float* __restrict__ b2c,
        const float* __restrict__ gamma, const float* __restrict__ beta,
        const float* __restrict__ fcw, const float* __restrict__ fcb,
        float* parts, float* dpart, float* ndot, int* cnts,
        float* __restrict__ out) {
    __shared__ uint4 ldsH[528], ldsL[528];
    __shared__ float red1[256], red2[256];
    __shared__ float pl[2 * NCHUNK2];
    __shared__ int lastNode, lastAll;
    int b = blockIdx.x;
    int node = b / NCHUNK2, chunk = b % NCHUNK2;
    int t0 = chunk * TC2;
    int tid = threadIdx.x;
    int* pcnt = cnts + node * 32;            // per-node barrier counter (own 128B line)
    int* ncnt = cnts + (18 + node) * 32;     // per-node election counter
    int* gcnt = cnts + 36 * 32;              // global election counter
    float h[16], s_sum, s_sq;
    conv2_compute(T1hi, T1lo, WBhi, WBlo, b2a, b2b, b2c, ldsH, ldsL,
                  node, t0, tid, h, &s_sum, &s_sq);
    red1[tid] = s_sum; red2[tid] = s_sq;
    __syncthreads();
    for (int off = 128; off > 0; off >>= 1) {
        if (tid < off) { red1[tid] += red1[tid + off]; red2[tid] += red2[tid + off]; }
        __syncthreads();
    }
    // ---- publish partials + per-node barrier (20 blocks per counter) ----
    if (tid == 0) {
        __hip_atomic_store(&parts[b * 2],     red1[0], __ATOMIC_RELEASE, __HIP_MEMORY_SCOPE_AGENT);
        __hip_atomic_store(&parts[b * 2 + 1], red2[0], __ATOMIC_RELEASE, __HIP_MEMORY_SCOPE_AGENT);
        __hip_atomic_fetch_add(pcnt, 1, __ATOMIC_RELEASE, __HIP_MEMORY_SCOPE_AGENT);
        while (__hip_atomic_load(pcnt, __ATOMIC_ACQUIRE, __HIP_MEMORY_SCOPE_AGENT) < NCHUNK2)
            __builtin_amdgcn_s_sleep(1);
    }
    __syncthreads();
    if (tid < 2 * NCHUNK2)
        pl[tid] = __hip_atomic_load(&parts[node * 2 * NCHUNK2 + tid],
                                    __ATOMIC_ACQUIRE, __HIP_MEMORY_SCOPE_AGENT);
    __syncthreads();
    // ---- stats finalize (fixed order, deterministic) ----
    float s = 0.f, q = 0.f;
    #pragma unroll
    for (int i = 0; i < NCHUNK2; ++i) { s += pl[2 * i]; q += pl[2 * i + 1]; }
    float cntf = (float)(T2LEN * 64);
    float mean = s / cntf;
    float var = q / cntf - mean * mean;
    float istd = rsqrtf(var + 1e-5f);
    float g = gamma[node], bt = beta[node];
    int l = tid & 63, w = tid >> 6;
    int co = w * 16 + (l & 15);
    float acc = 0.f;
    #pragma unroll
    for (int mt = 0; mt < 4; ++mt) {
        #pragma unroll
        for (int r = 0; r < 4; ++r) {
            int t = t0 + mt * 16 + (l >> 4) * 4 + r;
            if (t < T2LEN) {
                float v = fmaxf((h[mt * 4 + r] - mean) * istd * g + bt, 0.f);
                acc = fmaf(v, fcw[(t * NN + node) * 64 + co], acc);
            }
        }
    }
    red1[tid] = acc;
    __syncthreads();
    for (int off = 128; off > 0; off >>= 1) {
        if (tid < off) red1[tid] += red1[tid + off];
        __syncthreads();
    }
    if (tid == 0) {
        __hip_atomic_store(&dpart[b], red1[0], __ATOMIC_RELEASE, __HIP_MEMORY_SCOPE_AGENT);
        int o = __hip_atomic_fetch_add(ncnt, 1, __ATOMIC_ACQ_REL, __HIP_MEMORY_SCOPE_AGENT);
        lastNode = (o == NCHUNK2 - 1);
    }
    __syncthreads();
    if (!lastNode) return;
    // ---- node-last block: reduce its node's 20 dparts (fixed tree order) ----
    {
        float v = (tid < NCHUNK2)
            ? __hip_atomic_load(&dpart[node * NCHUNK2 + tid], __ATOMIC_ACQUIRE, __HIP_MEMORY_SCOPE_AGENT)
            : 0.f;
        red1[tid] = v;
        __syncthreads();
        for (int off = 128; off > 0; off >>= 1) {
            if (tid < off) red1[tid] += red1[tid + off];
            __syncthreads();
        }
        if (tid == 0) {
            __hip_atomic_store(&ndot[node], red1[0], __ATOMIC_RELEASE, __HIP_MEMORY_SCOPE_AGENT);
            int o2 = __hip_atomic_fetch_add(gcnt, 1, __ATOMIC_ACQ_REL, __HIP_MEMORY_SCOPE_AGENT);
            lastAll = (o2 == NN - 1);
        }
        __syncthreads();
    }
    if (!lastAll) return;
    // ---- global-last block: reduce 18 node sums ----
    {
        float v = (tid < NN)
            ? __hip_atomic_load(&ndot[tid], __ATOMIC_ACQUIRE, __HIP_MEMORY_SCOPE_AGENT)
            : 0.f;
        red1[tid] = v;
        __syncthreads();
        for (int off = 128; off > 0; off >>= 1) {
            if (tid < off) red1[tid] += red1[tid + off];
            __syncthreads();
        }
        if (tid == 0) out[0] = red1[0] + fcb[0];
    }
}

extern "C" void kernel_launch(void* const* d_in, const int* in_sizes, int n_in,
                              void* d_out, int out_size, void* d_ws, size_t ws_size,
                              hipStream_t stream) {
    const float* x     = (const float*)d_in[0];
    // d_in[1] edge_index, d_in[2] edge_weight: unused (ChebConv K=1 -> identity only)
    const float* w1a   = (const float*)d_in[3];
    const float* b1a   = (const float*)d_in[4];
    const float* w1b   = (const float*)d_in[5];
    const float* b1b   = (const float*)d_in[6];
    const float* w1c   = (const float*)d_in[7];
    const float* b1c   = (const float*)d_in[8];
    const float* chw   = (const float*)d_in[9];
    const float* chb   = (const float*)d_in[10];
    const float* w2a   = (const float*)d_in[11];
    const float* b2a   = (const float*)d_in[12];
    const float* w2b   = (const float*)d_in[13];
    const float* b2b   = (const float*)d_in[14];
    const float* w2c   = (const float*)d_in[15];
    const float* b2c   = (const float*)d_in[16];
    const float* gamma = (const float*)d_in[17];
    const float* beta  = (const float*)d_in[18];
    const float* fcw   = (const float*)d_in[19];
    const float* fcb   = (const float*)d_in[20];
    float* out = (float*)d_out;

    char* base = (char*)d_ws;
    unsigned short* T1hi  = (unsigned short*)(base);           // 2944512 B
    unsigned short* T1lo  = (unsigned short*)(base + 2944512); // 2944512 B
    unsigned short* WBhi  = (unsigned short*)(base + 5889024); // 73728 B
    unsigned short* WBlo  = (unsigned short*)(base + 5962752); // 73728 B
    float*          parts = (float*)(base + 6036480);          // 720 f -> 2880 B
    float*          dpart = (float*)(base + 6039360);          // 360 f -> 1440 B
    float*          ndot  = (float*)(base + 6040832);          // 18 f
    int*            cnts  = (int*)(base + 6041088);            // 37 x 128B

    k_fused1x<<<NCHUNK1 + PREPBLK, 256, 0, stream>>>(
        x, w1a, b1a, w1b, b1b, w1c, b1c, chw, chb,
        w2a, w2b, w2c, T1hi, T1lo, WBhi, WBlo, cnts);
    k_conv2dot<<<NBLK, 256, 0, stream>>>(
        T1hi, T1lo, WBhi, WBlo, b2a, b2b, b2c,
        gamma, beta, fcw, fcb, parts, dpart, ndot, cnts, out);
}

// Round 9
// 30.871 us; speedup vs baseline: 2.1650x; 1.5412x over previous
//
#include <hip/hip_runtime.h>
#include <math.h>

#define NN 18
#define T_STEPS 1280
#define T1LEN 1278   // T-2 (after conv1)
#define T2LEN 1276   // T-4 (after conv2)
#define PREPBLK 144  // 36864 / 256
#define TC2 62
#define NCHUNK2 ((T2LEN + TC2 - 1) / TC2)  // 21
#define NBLK (NCHUNK2 * NN)                // 378
#define DOT_BLOCKS 512

typedef __attribute__((ext_vector_type(8))) short short8;
typedef __attribute__((ext_vector_type(4))) float f32x4;

__device__ __forceinline__ unsigned short f2bf(float v) {
    unsigned u = __builtin_bit_cast(unsigned, v);
    u = u + 0x7fff + ((u >> 16) & 1);          // RNE
    return (unsigned short)(u >> 16);
}
__device__ __forceinline__ float bf2f(unsigned short h) {
    unsigned u = ((unsigned)h) << 16;
    return __builtin_bit_cast(float, u);
}
// swizzled ushort index for [row][c] bf16 tiles read as uint4 A-fragments
__device__ __forceinline__ int swz(int row, int c) {
    return row * 64 + (((c >> 3) ^ (row & 7)) << 3) + (c & 7);
}

// =========== K0: conv2 weight hi/lo split, layout [kb][col][klocal] (verified R3) ===========
__global__ void k_wprep(const float* __restrict__ wa, const float* __restrict__ wb,
                        const float* __restrict__ wc,
                        unsigned short* __restrict__ WBhi, unsigned short* __restrict__ WBlo) {
    int i = blockIdx.x * 256 + threadIdx.x;
    if (i >= 6 * 192 * 32) return;
    int klocal = i & 31;
    int col = (i >> 5) % 192;
    int kb = i / (192 * 32);
    int conv = col >> 6, co = col & 63;
    int k = kb >> 1, ci = (kb & 1) * 32 + klocal;
    const float* w = (conv == 0) ? wa : (conv == 1 ? wb : wc);
    float v = w[co * 192 + ci * 3 + k];
    unsigned short hi = f2bf(v);
    WBhi[i] = hi;
    WBlo[i] = f2bf(v - bf2f(hi));
}

// =========== K1: per (node, t-chunk): x -> conv1(GLU) -> cheb(MFMA) -> conv2(MFMA)
//               -> GLU -> T2 fp32 + BN partials.  T1 never hits global memory. ===========
__global__ __launch_bounds__(256) void k_fuseall(const float* __restrict__ x,
        const float* __restrict__ w1a, const float* __restrict__ b1a,
        const float* __restrict__ w1b, const float* __restrict__ b1b,
        const float* __restrict__ w1c, const float* __restrict__ b1c,
        const float* __restrict__ cw, const float* __restrict__ cb,
        const unsigned short* __restrict__ WBhi, const unsigned short* __restrict__ WBlo,
        const float* __restrict__ b2a, const float* __restrict__ b2b,
        const float* __restrict__ b2c,
        float* __restrict__ T2, float* __restrict__ parts) {
    __shared__ float xs[66];
    __shared__ uint4 t1H[512], t1L[512];   // 64 rows x 64 bf16 (swizzled)
    __shared__ uint4 t2H[528], t2L[528];   // 66 rows (rows 64-65 zero)
    __shared__ float red1[256], red2[256];
    int b = blockIdx.x;
    int node = b / NCHUNK2, chunk = b % NCHUNK2;
    int t0 = chunk * TC2;                  // T2 time base; T1 rows t0..t0+63
    int tid = threadIdx.x;
    int l = tid & 63, w = tid >> 6;

    // ---- stage + normalize 66 x values for this node ----
    if (tid < 66) {
        int xt = t0 + tid;
        float v = (xt < T_STEPS) ? x[xt * NN + node] : 0.f;
        xs[tid] = v / fmaxf(fabsf(v), 1e-12f);
    }
    __syncthreads();

    // ---- conv1 + GLU + relu -> t1 tile (bf16 hi/lo, swizzled) ----
    {
        unsigned short* tH = (unsigned short*)t1H;
        unsigned short* tL = (unsigned short*)t1L;
        int c = l;
        float wa0 = w1a[c*3], wa1 = w1a[c*3+1], wa2 = w1a[c*3+2];
        float wb0 = w1b[c*3], wb1 = w1b[c*3+1], wb2 = w1b[c*3+2];
        float wc0 = w1c[c*3], wc1 = w1c[c*3+1], wc2 = w1c[c*3+2];
        float ba = b1a[c], bb = b1b[c], bc = b1c[c];
        #pragma unroll
        for (int j = 0; j < 16; ++j) {
            int r = w * 16 + j;            // local T1 row, time tau = t0 + r
            float x0 = xs[r], x1 = xs[r + 1], x2 = xs[r + 2];
            float pa = fmaf(wa2, x2, fmaf(wa1, x1, fmaf(wa0, x0, ba)));
            float pb = fmaf(wb2, x2, fmaf(wb1, x1, fmaf(wb0, x0, bb)));
            float pc_ = fmaf(wc2, x2, fmaf(wc1, x1, fmaf(wc0, x0, bc)));
            float q = 1.0f / (1.0f + expf(-pb));
            float v = fmaxf(pa * q + pc_, 0.f);
            if (t0 + r >= T1LEN) v = 0.f;
            unsigned short hi = f2bf(v);
            int sw = swz(r, c);
            tH[sw] = hi;
            tL[sw] = f2bf(v - bf2f(hi));
        }
    }
    // ---- cheb B fragments from cw (hi/lo), wave w -> cols w*16..w*16+15 (verified) ----
    int d = w * 16 + (l & 15);
    short8 cbh[2], cbl[2];
    #pragma unroll
    for (int kb = 0; kb < 2; ++kb) {
        #pragma unroll
        for (int j = 0; j < 8; ++j) {
            float v = cw[(kb * 32 + (l >> 4) * 8 + j) * 64 + d];
            unsigned short hi = f2bf(v);
            cbh[kb][j] = (short)hi;
            cbl[kb][j] = (short)f2bf(v - bf2f(hi));
        }
    }
    __syncthreads();
    // ---- cheb MFMA: 64x64x64 split-bf16; wave w: cols d, M-tiles 0..3 ----
    {
        f32x4 acc[4];
        #pragma unroll
        for (int mt = 0; mt < 4; ++mt) acc[mt] = (f32x4){0.f,0.f,0.f,0.f};
        #pragma unroll
        for (int kb = 0; kb < 2; ++kb) {
            #pragma unroll
            for (int mt = 0; mt < 4; ++mt) {
                int row = mt * 16 + (l & 15);
                int cbi = kb * 4 + (l >> 4);
                int si = row * 8 + (cbi ^ (row & 7));
                short8 ah = __builtin_bit_cast(short8, t1H[si]);
                short8 al = __builtin_bit_cast(short8, t1L[si]);
                acc[mt] = __builtin_amdgcn_mfma_f32_16x16x32_bf16(ah, cbh[kb], acc[mt], 0, 0, 0);
                acc[mt] = __builtin_amdgcn_mfma_f32_16x16x32_bf16(al, cbh[kb], acc[mt], 0, 0, 0);
                acc[mt] = __builtin_amdgcn_mfma_f32_16x16x32_bf16(ah, cbl[kb], acc[mt], 0, 0, 0);
            }
        }
        float cbias = cb[d];
        unsigned short* tH = (unsigned short*)t2H;
        unsigned short* tL = (unsigned short*)t2L;
        #pragma unroll
        for (int mt = 0; mt < 4; ++mt) {
            #pragma unroll
            for (int r = 0; r < 4; ++r) {
                int row = mt * 16 + (l >> 4) * 4 + r;
                float v = fmaxf(acc[mt][r] + cbias, 0.f);
                if (t0 + row >= T1LEN) v = 0.f;
                unsigned short hi = f2bf(v);
                int sw = swz(row, d);
                tH[sw] = hi;
                tL[sw] = f2bf(v - bf2f(hi));
            }
        }
        // zero halo rows 64,65 (feed only discarded conv2 lanes)
        if (tid < 128) {
            int row = 64 + (tid >> 6), c = tid & 63;
            int sw = swz(row, c);
            tH[sw] = 0; tL[sw] = 0;
        }
    }
    __syncthreads();
    // ---- conv2 MFMA (verified pattern): A = t2 tile local rows, B = WB ----
    float s_sum = 0.f, s_sq = 0.f;
    {
        const uint4* wbh = (const uint4*)WBhi;
        const uint4* wbl = (const uint4*)WBlo;
        int co = w * 16 + (l & 15);
        f32x4 acc[4][3];
        #pragma unroll
        for (int mt = 0; mt < 4; ++mt)
            #pragma unroll
            for (int ct = 0; ct < 3; ++ct)
                acc[mt][ct] = (f32x4){0.f, 0.f, 0.f, 0.f};
        for (int kb = 0; kb < 6; ++kb) {
            short8 bh[3], bl[3];
            #pragma unroll
            for (int ct = 0; ct < 3; ++ct) {
                int col = (w + 4 * ct) * 16 + (l & 15);
                int gi = (kb * 192 + col) * 4 + (l >> 4);
                bh[ct] = __builtin_bit_cast(short8, wbh[gi]);
                bl[ct] = __builtin_bit_cast(short8, wbl[gi]);
            }
            #pragma unroll
            for (int mt = 0; mt < 4; ++mt) {
                int row = mt * 16 + (l & 15) + (kb >> 1);
                int cb2 = (kb & 1) * 4 + (l >> 4);
                int si = row * 8 + (cb2 ^ (row & 7));
                short8 ah = __builtin_bit_cast(short8, t2H[si]);
                short8 al = __builtin_bit_cast(short8, t2L[si]);
                acc[mt][0] = __builtin_amdgcn_mfma_f32_16x16x32_bf16(ah, bh[0], acc[mt][0], 0, 0, 0);
                acc[mt][1] = __builtin_amdgcn_mfma_f32_16x16x32_bf16(ah, bh[1], acc[mt][1], 0, 0, 0);
                acc[mt][2] = __builtin_amdgcn_mfma_f32_16x16x32_bf16(ah, bh[2], acc[mt][2], 0, 0, 0);
                acc[mt][0] = __builtin_amdgcn_mfma_f32_16x16x32_bf16(al, bh[0], acc[mt][0], 0, 0, 0);
                acc[mt][1] = __builtin_amdgcn_mfma_f32_16x16x32_bf16(al, bh[1], acc[mt][1], 0, 0, 0);
                acc[mt][2] = __builtin_amdgcn_mfma_f32_16x16x32_bf16(al, bh[2], acc[mt][2], 0, 0, 0);
                acc[mt][0] = __builtin_amdgcn_mfma_f32_16x16x32_bf16(ah, bl[0], acc[mt][0], 0, 0, 0);
                acc[mt][1] = __builtin_amdgcn_mfma_f32_16x16x32_bf16(ah, bl[1], acc[mt][1], 0, 0, 0);
                acc[mt][2] = __builtin_amdgcn_mfma_f32_16x16x32_bf16(ah, bl[2], acc[mt][2], 0, 0, 0);
            }
        }
        float ba = b2a[co], bb = b2b[co], bc = b2c[co];
        #pragma unroll
        for (int mt = 0; mt < 4; ++mt) {
            #pragma unroll
            for (int r = 0; r < 4; ++r) {
                int tl2 = mt * 16 + (l >> 4) * 4 + r;   // local t
                int t = t0 + tl2;
                if (tl2 < TC2 && t < T2LEN) {
                    float P = acc[mt][0][r] + ba, Q = acc[mt][1][r] + bb, Cc = acc[mt][2][r] + bc;
                    float qs = 1.f / (1.f + expf(-Q));
                    float hv = fmaxf(fmaf(P, qs, Cc), 0.f);
                    T2[(t * NN + node) * 64 + co] = hv;
                    s_sum += hv;
                    s_sq = fmaf(hv, hv, s_sq);
                }
            }
        }
    }
    red1[tid] = s_sum; red2[tid] = s_sq;
    __syncthreads();
    for (int off = 128; off > 0; off >>= 1) {
        if (tid < off) { red1[tid] += red1[tid + off]; red2[tid] += red2[tid + off]; }
        __syncthreads();
    }
    if (tid == 0) {
        parts[b * 2]     = red1[0];
        parts[b * 2 + 1] = red2[0];
    }
}

// =========== K2: redundant fixed-order stats finalize + BN + relu + dot (float4) ===========
__global__ __launch_bounds__(256) void k_dot2(const float* __restrict__ T2,
        const float* __restrict__ parts,
        const float* __restrict__ gamma, const float* __restrict__ beta,
        const float* __restrict__ fcw, float* __restrict__ dpart) {
    __shared__ float sm[NN * 4];   // mean, istd, gamma, beta per node
    if (threadIdx.x < NN) {
        int n = threadIdx.x;
        float s = 0.f, q = 0.f;
        for (int i = 0; i < NCHUNK2; ++i) {           // fixed order, deterministic
            s += parts[(n * NCHUNK2 + i) * 2];
            q += parts[(n * NCHUNK2 + i) * 2 + 1];
        }
        float cnt = (float)(T2LEN * 64);
        float mean = s / cnt;
        float var = q / cnt - mean * mean;
        sm[n * 4]     = mean;
        sm[n * 4 + 1] = rsqrtf(var + 1e-5f);
        sm[n * 4 + 2] = gamma[n];
        sm[n * 4 + 3] = beta[n];
    }
    __syncthreads();
    float acc = 0.f;
    const int total4 = T2LEN * NN * 64 / 4;
    const float4* T24 = (const float4*)T2;
    const float4* fw4 = (const float4*)fcw;
    for (int i = blockIdx.x * 256 + threadIdx.x; i < total4; i += DOT_BLOCKS * 256) {
        float4 t = T24[i];
        float4 f = fw4[i];
        int n = (i >> 4) % NN;
        float mu = sm[n * 4], is = sm[n * 4 + 1], g = sm[n * 4 + 2], bt = sm[n * 4 + 3];
        float v0 = fmaxf((t.x - mu) * is * g + bt, 0.f);
        float v1 = fmaxf((t.y - mu) * is * g + bt, 0.f);
        float v2 = fmaxf((t.z - mu) * is * g + bt, 0.f);
        float v3 = fmaxf((t.w - mu) * is * g + bt, 0.f);
        acc = fmaf(v0, f.x, acc);
        acc = fmaf(v1, f.y, acc);
        acc = fmaf(v2, f.z, acc);
        acc = fmaf(v3, f.w, acc);
    }
    __shared__ float r[256];
    r[threadIdx.x] = acc;
    __syncthreads();
    for (int off = 128; off > 0; off >>= 1) {
        if (threadIdx.x < off) r[threadIdx.x] += r[threadIdx.x + off];
        __syncthreads();
    }
    if (threadIdx.x == 0) dpart[blockIdx.x] = r[0];
}

// =========== K3: final reduce + fc_b ===========
__global__ __launch_bounds__(512) void k_final(const float* __restrict__ dpart,
                                               const float* __restrict__ fcb,
                                               float* __restrict__ out) {
    __shared__ float r[512];
    r[threadIdx.x] = dpart[threadIdx.x];
    __syncthreads();
    for (int off = 256; off > 0; off >>= 1) {
        if (threadIdx.x < off) r[threadIdx.x] += r[threadIdx.x + off];
        __syncthreads();
    }
    if (threadIdx.x == 0) out[0] = r[0] + fcb[0];
}

extern "C" void kernel_launch(void* const* d_in, const int* in_sizes, int n_in,
                              void* d_out, int out_size, void* d_ws, size_t ws_size,
                              hipStream_t stream) {
    const float* x     = (const float*)d_in[0];
    // d_in[1] edge_index, d_in[2] edge_weight: unused (ChebConv K=1 -> identity only)
    const float* w1a   = (const float*)d_in[3];
    const float* b1a   = (const float*)d_in[4];
    const float* w1b   = (const float*)d_in[5];
    const float* b1b   = (const float*)d_in[6];
    const float* w1c   = (const float*)d_in[7];
    const float* b1c   = (const float*)d_in[8];
    const float* chw   = (const float*)d_in[9];
    const float* chb   = (const float*)d_in[10];
    const float* w2a   = (const float*)d_in[11];
    const float* b2a   = (const float*)d_in[12];
    const float* w2b   = (const float*)d_in[13];
    const float* b2b   = (const float*)d_in[14];
    const float* w2c   = (const float*)d_in[15];
    const float* b2c   = (const float*)d_in[16];
    const float* gamma = (const float*)d_in[17];
    const float* beta  = (const float*)d_in[18];
    const float* fcw   = (const float*)d_in[19];
    const float* fcb   = (const float*)d_in[20];
    float* out = (float*)d_out;

    char* base = (char*)d_ws;
    float*          T2v   = (float*)(base);                    // 1469952 f = 5879808 B
    unsigned short* WBhi  = (unsigned short*)(base + 5879808); // 73728 B
    unsigned short* WBlo  = (unsigned short*)(base + 5953536); // 73728 B
    float*          parts = (float*)(base + 6027264);          // 756 f
    float*          dpart = (float*)(base + 6030336);          // 512 f

    k_wprep<<<PREPBLK, 256, 0, stream>>>(w2a, w2b, w2c, WBhi, WBlo);
    k_fuseall<<<NBLK, 256, 0, stream>>>(
        x, w1a, b1a, w1b, b1b, w1c, b1c, chw, chb,
        WBhi, WBlo, b2a, b2b, b2c, T2v, parts);
    k_dot2<<<DOT_BLOCKS, 256, 0, stream>>>(T2v, parts, gamma, beta, fcw, dpart);
    k_final<<<1, 512, 0, stream>>>(dpart, fcb, out);
}